// Round 6
// baseline (57.524 us; speedup 1.0000x reference)
//
#include <hip/hip_runtime.h>

#define BS 8
#define B2 16
#define S 2048
#define H 2048
#define PAD_ID 0

constexpr int BLOCKS_PER_PAIR = 256;
constexpr int WAVES_PER_BLOCK = 4;
constexpr int S_PER_WAVE = S / (BLOCKS_PER_PAIR * WAVES_PER_BLOCK); // 2

// Single fused kernel: per-block ids scan + paired streaming dot products +
// hinge; loss accumulated straight into out[0] via one atomicAdd per block
// (out[0] zeroed by a 4-byte memsetAsync before launch).
__global__ __launch_bounds__(256) void main_kernel(
    const float* __restrict__ hidden,    // [B2, S, H]
    const int*   __restrict__ input_ids, // [B2, S]
    const float* __restrict__ unsafe,    // [BS]
    const int*   __restrict__ risk_type, // [BS]
    const float* __restrict__ emb,       // [N_RISK, H]
    const float* __restrict__ v_w,       // [H]
    float* __restrict__ out)             // [17]
{
    const int b    = blockIdx.x / BLOCKS_PER_PAIR;
    const int blk  = blockIdx.x % BLOCKS_PER_PAIR;
    const int wave = threadIdx.x >> 6;
    const int lane = threadIdx.x & 63;
    const int rt   = risk_type[b];

    // --- combined per-lane weights (emb row + v_w are L1/L2-resident) ---
    float4 w[8];
    {
        const float4* embv = (const float4*)(emb + (size_t)rt * H);
        const float4* vwv  = (const float4*)v_w;
#pragma unroll
        for (int c = 0; c < 8; ++c) {
            int i = c * 64 + lane;
            float4 e = embv[i];
            float4 v = vwv[i];
            w[c] = make_float4(e.x * v.x, e.y * v.y, e.z * v.z, e.w * v.w);
        }
    }

    // --- in-block ids scan (2x8KB int4 loads, L2-resident across blocks) ---
    int my_cind = S, my_rind = S, my_div = S;
    {
        const int4* cid4 = (const int4*)(input_ids + b * S);
        const int4* rid4 = (const int4*)(input_ids + (b + BS) * S);
        for (int i = threadIdx.x; i < S / 4; i += 256) {
            int4 c4 = cid4[i];
            int4 r4 = rid4[i];
            int base = i * 4;
            int cv[4] = {c4.x, c4.y, c4.z, c4.w};
            int rv[4] = {r4.x, r4.y, r4.z, r4.w};
#pragma unroll
            for (int j = 0; j < 4; ++j) {
                int s = base + j;
                if (cv[j] == PAD_ID && s < my_cind) my_cind = s;
                if (rv[j] == PAD_ID && s < my_rind) my_rind = s;
                if (cv[j] != rv[j]  && s < my_div)  my_div  = s;
            }
        }
#pragma unroll
        for (int off = 32; off > 0; off >>= 1) {
            my_cind = min(my_cind, __shfl_xor(my_cind, off, 64));
            my_rind = min(my_rind, __shfl_xor(my_rind, off, 64));
            my_div  = min(my_div,  __shfl_xor(my_div,  off, 64));
        }
    }
    __shared__ int s_c[WAVES_PER_BLOCK], s_r[WAVES_PER_BLOCK], s_d[WAVES_PER_BLOCK];
    if (lane == 0) { s_c[wave] = my_cind; s_r[wave] = my_rind; s_d[wave] = my_div; }
    __syncthreads();
    const int c_ind = min(min(s_c[0], s_c[1]), min(s_c[2], s_c[3]));
    const int r_pad = min(min(s_r[0], s_r[1]), min(s_r[2], s_r[3]));
    const int fdiv  = min(min(s_d[0], s_d[1]), min(s_d[2], s_d[3]));
    const bool has_div = (fdiv < S);
    const int dv    = has_div ? fdiv : (S - 1);
    const int end   = has_div ? max(c_ind, r_pad) : S;
    const int r_ind = has_div ? r_pad : c_ind;
    const float u   = unsafe[b];

    // --- streaming paired dot products + fused hinge (2 rows in flight) ---
    const float4* hc = (const float4*)(hidden + (size_t)b * S * H);
    const float4* hr = (const float4*)(hidden + (size_t)(b + BS) * S * H);
    const int s0 = (blk * WAVES_PER_BLOCK + wave) * S_PER_WAVE;
    float hinge = 0.f;

    {
        const int sA = s0, sB = s0 + 1;
        const float4* rcA = hc + (size_t)sA * (H / 4);
        const float4* rrA = hr + (size_t)sA * (H / 4);
        const float4* rcB = hc + (size_t)sB * (H / 4);
        const float4* rrB = hr + (size_t)sB * (H / 4);
        float acA = 0.f, arA = 0.f, acB = 0.f, arB = 0.f;
#pragma unroll
        for (int c = 0; c < 8; ++c) {
            float4 xA = rcA[c * 64 + lane];
            float4 yA = rrA[c * 64 + lane];
            float4 xB = rcB[c * 64 + lane];
            float4 yB = rrB[c * 64 + lane];
            acA += xA.x * w[c].x + xA.y * w[c].y + xA.z * w[c].z + xA.w * w[c].w;
            arA += yA.x * w[c].x + yA.y * w[c].y + yA.z * w[c].z + yA.w * w[c].w;
            acB += xB.x * w[c].x + xB.y * w[c].y + xB.z * w[c].z + xB.w * w[c].w;
            arB += yB.x * w[c].x + yB.y * w[c].y + yB.z * w[c].z + yB.w * w[c].w;
        }
#pragma unroll
        for (int off = 32; off > 0; off >>= 1) {
            acA += __shfl_xor(acA, off, 64);
            arA += __shfl_xor(arA, off, 64);
            acB += __shfl_xor(acB, off, 64);
            arB += __shfl_xor(arB, off, 64);
        }
        if (lane == 0) {
            if (sA >= dv && sA < end) {
                float h = u - (acA - arA);
                hinge += (h > 0.f) ? h : 0.f;
            }
            if (sB >= dv && sB < end) {
                float h = u - (acB - arB);
                hinge += (h > 0.f) ? h : 0.f;
            }
            if (sA == c_ind - 1) out[1 + b] = acA;
            if (sB == c_ind - 1) out[1 + b] = acB;
            if (sA == r_ind - 1) out[9 + b] = arA;
            if (sB == r_ind - 1) out[9 + b] = arB;
        }
    }

    // --- block combine + one atomic contribution to the loss ---
    __shared__ float s_h[WAVES_PER_BLOCK];
    if (lane == 0) s_h[wave] = hinge;
    __syncthreads();
    if (threadIdx.x == 0) {
        float blockHinge = (s_h[0] + s_h[1]) + (s_h[2] + s_h[3]);
        if (blockHinge != 0.f) {
            float cnt = (float)max(end - dv, 1);
            atomicAdd(&out[0], blockHinge / (cnt * (float)BS));
        }
    }
}

extern "C" void kernel_launch(void* const* d_in, const int* in_sizes, int n_in,
                              void* d_out, int out_size, void* d_ws, size_t ws_size,
                              hipStream_t stream) {
    const float* hidden    = (const float*)d_in[0];
    const int*   input_ids = (const int*)d_in[1];
    const float* unsafe    = (const float*)d_in[2];
    const int*   risk_type = (const int*)d_in[3];
    const float* emb       = (const float*)d_in[4];
    const float* v_w       = (const float*)d_in[5];
    float* out = (float*)d_out;

    hipMemsetAsync(out, 0, sizeof(float), stream); // out[0] accumulator; out not re-poisoned between replays
    main_kernel<<<BS * BLOCKS_PER_PAIR, 256, 0, stream>>>(
        hidden, input_ids, unsafe, risk_type, emb, v_w, out);
}

// Round 7
// 50.760 us; speedup vs baseline: 1.1333x; 1.1333x over previous
//
#include <hip/hip_runtime.h>

#define BS 8
#define B2 16
#define S 2048
#define H 2048
#define PAD_ID 0

constexpr int BLOCKS_PER_PAIR = 128;
constexpr int WAVES_PER_BLOCK = 4;
constexpr int S_PER_WAVE = S / (BLOCKS_PER_PAIR * WAVES_PER_BLOCK); // 4

// Single fused kernel (round-5 proven body): per-block ids scan + paired
// streaming dot products + hinge. Loss goes straight into out[0] via one
// atomicAdd per block that has a nonzero hinge window (~25 blocks/pair);
// out[0] is zeroed by a 4-byte fill issued before the main kernel.
__global__ __launch_bounds__(256) void main_kernel(
    const float* __restrict__ hidden,    // [B2, S, H]
    const int*   __restrict__ input_ids, // [B2, S]
    const float* __restrict__ unsafe,    // [BS]
    const int*   __restrict__ risk_type, // [BS]
    const float* __restrict__ emb,       // [N_RISK, H]
    const float* __restrict__ v_w,       // [H]
    float* __restrict__ out)             // [17]
{
    const int b    = blockIdx.x / BLOCKS_PER_PAIR;
    const int blk  = blockIdx.x % BLOCKS_PER_PAIR;
    const int wave = threadIdx.x >> 6;
    const int lane = threadIdx.x & 63;
    const int rt   = risk_type[b];

    // --- combined per-lane weights (emb row + v_w are L1/L2-resident) ---
    float4 w[8];
    {
        const float4* embv = (const float4*)(emb + (size_t)rt * H);
        const float4* vwv  = (const float4*)v_w;
#pragma unroll
        for (int c = 0; c < 8; ++c) {
            int i = c * 64 + lane;
            float4 e = embv[i];
            float4 v = vwv[i];
            w[c] = make_float4(e.x * v.x, e.y * v.y, e.z * v.z, e.w * v.w);
        }
    }

    // --- in-block ids scan (2x8KB int4 loads, L2-resident across blocks) ---
    int my_cind = S, my_rind = S, my_div = S;
    {
        const int4* cid4 = (const int4*)(input_ids + b * S);
        const int4* rid4 = (const int4*)(input_ids + (b + BS) * S);
        for (int i = threadIdx.x; i < S / 4; i += 256) {
            int4 c4 = cid4[i];
            int4 r4 = rid4[i];
            int base = i * 4;
            int cv[4] = {c4.x, c4.y, c4.z, c4.w};
            int rv[4] = {r4.x, r4.y, r4.z, r4.w};
#pragma unroll
            for (int j = 0; j < 4; ++j) {
                int s = base + j;
                if (cv[j] == PAD_ID && s < my_cind) my_cind = s;
                if (rv[j] == PAD_ID && s < my_rind) my_rind = s;
                if (cv[j] != rv[j]  && s < my_div)  my_div  = s;
            }
        }
#pragma unroll
        for (int off = 32; off > 0; off >>= 1) {
            my_cind = min(my_cind, __shfl_xor(my_cind, off, 64));
            my_rind = min(my_rind, __shfl_xor(my_rind, off, 64));
            my_div  = min(my_div,  __shfl_xor(my_div,  off, 64));
        }
    }
    __shared__ int s_c[WAVES_PER_BLOCK], s_r[WAVES_PER_BLOCK], s_d[WAVES_PER_BLOCK];
    if (lane == 0) { s_c[wave] = my_cind; s_r[wave] = my_rind; s_d[wave] = my_div; }
    __syncthreads();
    const int c_ind = min(min(s_c[0], s_c[1]), min(s_c[2], s_c[3]));
    const int r_pad = min(min(s_r[0], s_r[1]), min(s_r[2], s_r[3]));
    const int fdiv  = min(min(s_d[0], s_d[1]), min(s_d[2], s_d[3]));
    const bool has_div = (fdiv < S);
    const int dv    = has_div ? fdiv : (S - 1);
    const int end   = has_div ? max(c_ind, r_pad) : S;
    const int r_ind = has_div ? r_pad : c_ind;
    const float u   = unsafe[b];

    // --- streaming paired dot products + fused hinge (2 rows in flight) ---
    const float4* hc = (const float4*)(hidden + (size_t)b * S * H);
    const float4* hr = (const float4*)(hidden + (size_t)(b + BS) * S * H);
    const int s0 = (blk * WAVES_PER_BLOCK + wave) * S_PER_WAVE;
    float hinge = 0.f;

#pragma unroll
    for (int r = 0; r < S_PER_WAVE; r += 2) {
        const int sA = s0 + r;
        const int sB = sA + 1;
        const float4* rcA = hc + (size_t)sA * (H / 4);
        const float4* rrA = hr + (size_t)sA * (H / 4);
        const float4* rcB = hc + (size_t)sB * (H / 4);
        const float4* rrB = hr + (size_t)sB * (H / 4);
        float acA = 0.f, arA = 0.f, acB = 0.f, arB = 0.f;
#pragma unroll
        for (int c = 0; c < 8; ++c) {
            float4 xA = rcA[c * 64 + lane];
            float4 yA = rrA[c * 64 + lane];
            float4 xB = rcB[c * 64 + lane];
            float4 yB = rrB[c * 64 + lane];
            acA += xA.x * w[c].x + xA.y * w[c].y + xA.z * w[c].z + xA.w * w[c].w;
            arA += yA.x * w[c].x + yA.y * w[c].y + yA.z * w[c].z + yA.w * w[c].w;
            acB += xB.x * w[c].x + xB.y * w[c].y + xB.z * w[c].z + xB.w * w[c].w;
            arB += yB.x * w[c].x + yB.y * w[c].y + yB.z * w[c].z + yB.w * w[c].w;
        }
#pragma unroll
        for (int off = 32; off > 0; off >>= 1) {
            acA += __shfl_xor(acA, off, 64);
            arA += __shfl_xor(arA, off, 64);
            acB += __shfl_xor(acB, off, 64);
            arB += __shfl_xor(arB, off, 64);
        }
        if (lane == 0) {
            if (sA >= dv && sA < end) {
                float h = u - (acA - arA);
                hinge += (h > 0.f) ? h : 0.f;
            }
            if (sB >= dv && sB < end) {
                float h = u - (acB - arB);
                hinge += (h > 0.f) ? h : 0.f;
            }
            if (sA == c_ind - 1) out[1 + b] = acA;
            if (sB == c_ind - 1) out[1 + b] = acB;
            if (sA == r_ind - 1) out[9 + b] = arA;
            if (sB == r_ind - 1) out[9 + b] = arB;
        }
    }

    // --- block combine + one atomic contribution to the loss ---
    __shared__ float s_h[WAVES_PER_BLOCK];
    if (lane == 0) s_h[wave] = hinge;
    __syncthreads();
    if (threadIdx.x == 0) {
        float blockHinge = (s_h[0] + s_h[1]) + (s_h[2] + s_h[3]);
        if (blockHinge != 0.f) {
            float cnt = (float)max(end - dv, 1);
            atomicAdd(&out[0], blockHinge / (cnt * (float)BS));
        }
    }
}

extern "C" void kernel_launch(void* const* d_in, const int* in_sizes, int n_in,
                              void* d_out, int out_size, void* d_ws, size_t ws_size,
                              hipStream_t stream) {
    const float* hidden    = (const float*)d_in[0];
    const int*   input_ids = (const int*)d_in[1];
    const float* unsafe    = (const float*)d_in[2];
    const int*   risk_type = (const int*)d_in[3];
    const float* emb       = (const float*)d_in[4];
    const float* v_w       = (const float*)d_in[5];
    float* out = (float*)d_out;

    hipMemsetAsync(out, 0, sizeof(float), stream); // zero the loss accumulator
    main_kernel<<<BS * BLOCKS_PER_PAIR, 256, 0, stream>>>(
        hidden, input_ids, unsafe, risk_type, emb, v_w, out);
}

// Round 8
// 18.613 us; speedup vs baseline: 3.0906x; 2.7272x over previous
//
#include <hip/hip_runtime.h>

#define BS 8
#define B2 16
#define S 2048
#define H 2048
#define PAD_ID 0

constexpr int BLOCKS_PER_PAIR = 128;
constexpr int WAVES_PER_BLOCK = 4;
constexpr int WAVES_PER_PAIR  = BLOCKS_PER_PAIR * WAVES_PER_BLOCK; // 512

// ws layout: [0..63]  int idxbuf[BS*2] (div, end)
//            [256..]  float partial[BS*128]
//
// Key observation: rewards[b][s] is consumed ONLY at s in
// {c_ind-1} u {r_ind-1} u [div, end). All other dot products are dead work.
// Each block scans ids (L2-resident, proven round-5 prologue), builds the
// live-task count, and its waves grid-stride over the task list. Correct for
// arbitrary inputs (worst case end=S degenerates to full streaming).

__global__ __launch_bounds__(256) void main_kernel(
    const float* __restrict__ hidden,    // [B2, S, H]
    const int*   __restrict__ input_ids, // [B2, S]
    const float* __restrict__ unsafe,    // [BS]
    const int*   __restrict__ risk_type, // [BS]
    const float* __restrict__ emb,       // [N_RISK, H]
    const float* __restrict__ v_w,       // [H]
    int*   __restrict__ idxbuf,          // [BS*2]
    float* __restrict__ partial,         // [BS*128]
    float* __restrict__ out)             // [17]
{
    const int b    = blockIdx.x / BLOCKS_PER_PAIR;
    const int blk  = blockIdx.x % BLOCKS_PER_PAIR;
    const int wave = threadIdx.x >> 6;
    const int lane = threadIdx.x & 63;

    // --- in-block ids scan (2x8KB int4 loads, L2-resident; proven) ---
    int my_cind = S, my_rind = S, my_div = S;
    {
        const int4* cid4 = (const int4*)(input_ids + b * S);
        const int4* rid4 = (const int4*)(input_ids + (b + BS) * S);
#pragma unroll
        for (int it = 0; it < 2; ++it) {
            int i = threadIdx.x + it * 256;
            int4 c4 = cid4[i];
            int4 r4 = rid4[i];
            int base = i * 4;
            int cv[4] = {c4.x, c4.y, c4.z, c4.w};
            int rv[4] = {r4.x, r4.y, r4.z, r4.w};
#pragma unroll
            for (int j = 0; j < 4; ++j) {
                int s = base + j;
                if (cv[j] == PAD_ID && s < my_cind) my_cind = s;
                if (rv[j] == PAD_ID && s < my_rind) my_rind = s;
                if (cv[j] != rv[j]  && s < my_div)  my_div  = s;
            }
        }
#pragma unroll
        for (int off = 32; off > 0; off >>= 1) {
            my_cind = min(my_cind, __shfl_xor(my_cind, off, 64));
            my_rind = min(my_rind, __shfl_xor(my_rind, off, 64));
            my_div  = min(my_div,  __shfl_xor(my_div,  off, 64));
        }
    }
    __shared__ int s_c[WAVES_PER_BLOCK], s_r[WAVES_PER_BLOCK], s_d[WAVES_PER_BLOCK];
    if (lane == 0) { s_c[wave] = my_cind; s_r[wave] = my_rind; s_d[wave] = my_div; }
    __syncthreads();
    const int c_ind = min(min(s_c[0], s_c[1]), min(s_c[2], s_c[3]));
    const int r_pad = min(min(s_r[0], s_r[1]), min(s_r[2], s_r[3]));
    const int fdiv  = min(min(s_d[0], s_d[1]), min(s_d[2], s_d[3]));
    const bool has_div = (fdiv < S);
    const int dv    = has_div ? fdiv : (S - 1);
    const int end   = has_div ? max(c_ind, r_pad) : S;
    const int r_ind = has_div ? r_pad : c_ind;

    // --- live task list: t=0 -> chosen score, t=1 -> rejected score,
    //     t>=2 -> hinge row s = dv + (t-2) ---
    const int nlive = end - dv;
    const int ntask = (nlive > 0 ? nlive : 0) + 2;
    const int t0 = blk * WAVES_PER_BLOCK + wave;

    float hinge = 0.f;
    if (t0 < ntask) {
        const int rt = risk_type[b];
        float4 w[8];
        {
            const float4* embv = (const float4*)(emb + (size_t)rt * H);
            const float4* vwv  = (const float4*)v_w;
#pragma unroll
            for (int c = 0; c < 8; ++c) {
                int i = c * 64 + lane;
                float4 e = embv[i];
                float4 v = vwv[i];
                w[c] = make_float4(e.x * v.x, e.y * v.y, e.z * v.z, e.w * v.w);
            }
        }
        const float u = unsafe[b];
        const float4* hc = (const float4*)(hidden + (size_t)b * S * H);
        const float4* hr = (const float4*)(hidden + (size_t)(b + BS) * S * H);

        for (int t = t0; t < ntask; t += WAVES_PER_PAIR) {
            if (t == 0) {
                const int s = max(c_ind - 1, 0);
                const float4* rc = hc + (size_t)s * (H / 4);
                float ac = 0.f;
#pragma unroll
                for (int c = 0; c < 8; ++c) {
                    float4 x = rc[c * 64 + lane];
                    ac += x.x * w[c].x + x.y * w[c].y + x.z * w[c].z + x.w * w[c].w;
                }
#pragma unroll
                for (int off = 32; off > 0; off >>= 1) ac += __shfl_xor(ac, off, 64);
                if (lane == 0) out[1 + b] = ac;
            } else if (t == 1) {
                const int s = max(r_ind - 1, 0);
                const float4* rr = hr + (size_t)s * (H / 4);
                float ar = 0.f;
#pragma unroll
                for (int c = 0; c < 8; ++c) {
                    float4 y = rr[c * 64 + lane];
                    ar += y.x * w[c].x + y.y * w[c].y + y.z * w[c].z + y.w * w[c].w;
                }
#pragma unroll
                for (int off = 32; off > 0; off >>= 1) ar += __shfl_xor(ar, off, 64);
                if (lane == 0) out[9 + b] = ar;
            } else {
                const int s = dv + (t - 2);
                const float4* rc = hc + (size_t)s * (H / 4);
                const float4* rr = hr + (size_t)s * (H / 4);
                float ac = 0.f, ar = 0.f;
#pragma unroll
                for (int c = 0; c < 8; ++c) {
                    float4 x = rc[c * 64 + lane];
                    float4 y = rr[c * 64 + lane];
                    ac += x.x * w[c].x + x.y * w[c].y + x.z * w[c].z + x.w * w[c].w;
                    ar += y.x * w[c].x + y.y * w[c].y + y.z * w[c].z + y.w * w[c].w;
                }
#pragma unroll
                for (int off = 32; off > 0; off >>= 1) {
                    ac += __shfl_xor(ac, off, 64);
                    ar += __shfl_xor(ar, off, 64);
                }
                float h = u - (ac - ar);
                hinge += (h > 0.f) ? h : 0.f;   // all lanes hold same value
            }
        }
    }

    // --- block combine (uniform: every block writes its partial) ---
    __shared__ float s_h[WAVES_PER_BLOCK];
    if (lane == 0) s_h[wave] = hinge;
    __syncthreads();
    if (threadIdx.x == 0) {
        partial[b * BLOCKS_PER_PAIR + blk] = (s_h[0] + s_h[1]) + (s_h[2] + s_h[3]);
        if (blk == 0) { idxbuf[b * 2] = dv; idxbuf[b * 2 + 1] = end; }
    }
}

// ---- Kernel 2: deterministic loss reduction (proven round-5 tail) ---------
__global__ __launch_bounds__(512) void loss_kernel(
    const float* __restrict__ partial, // [BS*128]
    const int*   __restrict__ idxbuf,  // [BS*2]
    float* __restrict__ out)           // [17]
{
    const int b    = threadIdx.x >> 6;
    const int lane = threadIdx.x & 63;
    float s = partial[b * BLOCKS_PER_PAIR + lane]
            + partial[b * BLOCKS_PER_PAIR + 64 + lane];
#pragma unroll
    for (int off = 32; off > 0; off >>= 1)
        s += __shfl_xor(s, off, 64);

    __shared__ float s_per[BS];
    if (lane == 0) {
        int cnt = max(idxbuf[b * 2 + 1] - idxbuf[b * 2], 1);
        s_per[b] = s / (float)cnt;
    }
    __syncthreads();
    if (threadIdx.x == 0) {
        float t = 0.f;
#pragma unroll
        for (int i = 0; i < BS; ++i) t += s_per[i];
        out[0] = t / (float)BS;
    }
}

extern "C" void kernel_launch(void* const* d_in, const int* in_sizes, int n_in,
                              void* d_out, int out_size, void* d_ws, size_t ws_size,
                              hipStream_t stream) {
    const float* hidden    = (const float*)d_in[0];
    const int*   input_ids = (const int*)d_in[1];
    const float* unsafe    = (const float*)d_in[2];
    const int*   risk_type = (const int*)d_in[3];
    const float* emb       = (const float*)d_in[4];
    const float* v_w       = (const float*)d_in[5];
    float* out = (float*)d_out;

    int*   idxbuf  = (int*)d_ws;
    float* partial = (float*)((char*)d_ws + 256);

    main_kernel<<<BS * BLOCKS_PER_PAIR, 256, 0, stream>>>(
        hidden, input_ids, unsafe, risk_type, emb, v_w, idxbuf, partial, out);
    loss_kernel<<<1, 512, 0, stream>>>(partial, idxbuf, out);
}

// Round 9
// 16.695 us; speedup vs baseline: 3.4455x; 1.1148x over previous
//
#include <hip/hip_runtime.h>

#define BS 8
#define B2 16
#define S 2048
#define H 2048
#define PAD_ID 0

constexpr int BLOCKS_PER_PAIR = 64;
constexpr int WAVES_PER_BLOCK = 4;
constexpr int WAVES_PER_PAIR  = BLOCKS_PER_PAIR * WAVES_PER_BLOCK; // 256

// ws layout: [0..63]  int idxbuf[BS*2] (div, end)
//            [256..]  float partial[BS*64]
//
// rewards[b][s] is consumed ONLY at s in {c_ind-1} u {r_ind-1} u [div,end).
// Each block scans ids (L2-resident), then its waves grid-stride the live
// task list. Correct for arbitrary inputs (worst case degenerates to full
// streaming at 8 tasks/wave).

__global__ __launch_bounds__(256) void main_kernel(
    const float* __restrict__ hidden,    // [B2, S, H]
    const int*   __restrict__ input_ids, // [B2, S]
    const float* __restrict__ unsafe,    // [BS]
    const int*   __restrict__ risk_type, // [BS]
    const float* __restrict__ emb,       // [N_RISK, H]
    const float* __restrict__ v_w,       // [H]
    int*   __restrict__ idxbuf,          // [BS*2]
    float* __restrict__ partial,         // [BS*64]
    float* __restrict__ out)             // [17]
{
    const int b    = blockIdx.x / BLOCKS_PER_PAIR;
    const int blk  = blockIdx.x % BLOCKS_PER_PAIR;
    const int wave = threadIdx.x >> 6;
    const int lane = threadIdx.x & 63;

    // --- combined per-lane weights, hoisted ABOVE the scan so the L2 loads
    //     overlap the scan's loads (removes a serial step from the chain) ---
    const int rt = risk_type[b];
    float4 w[8];
    {
        const float4* embv = (const float4*)(emb + (size_t)rt * H);
        const float4* vwv  = (const float4*)v_w;
#pragma unroll
        for (int c = 0; c < 8; ++c) {
            int i = c * 64 + lane;
            float4 e = embv[i];
            float4 v = vwv[i];
            w[c] = make_float4(e.x * v.x, e.y * v.y, e.z * v.z, e.w * v.w);
        }
    }
    const float u = unsafe[b];

    // --- in-block ids scan (2x8KB int4 loads, L2-resident) ---
    int my_cind = S, my_rind = S, my_div = S;
    {
        const int4* cid4 = (const int4*)(input_ids + b * S);
        const int4* rid4 = (const int4*)(input_ids + (b + BS) * S);
#pragma unroll
        for (int it = 0; it < 2; ++it) {
            int i = threadIdx.x + it * 256;
            int4 c4 = cid4[i];
            int4 r4 = rid4[i];
            int base = i * 4;
            int cv[4] = {c4.x, c4.y, c4.z, c4.w};
            int rv[4] = {r4.x, r4.y, r4.z, r4.w};
#pragma unroll
            for (int j = 0; j < 4; ++j) {
                int s = base + j;
                if (cv[j] == PAD_ID && s < my_cind) my_cind = s;
                if (rv[j] == PAD_ID && s < my_rind) my_rind = s;
                if (cv[j] != rv[j]  && s < my_div)  my_div  = s;
            }
        }
#pragma unroll
        for (int off = 32; off > 0; off >>= 1) {
            my_cind = min(my_cind, __shfl_xor(my_cind, off, 64));
            my_rind = min(my_rind, __shfl_xor(my_rind, off, 64));
            my_div  = min(my_div,  __shfl_xor(my_div,  off, 64));
        }
    }
    __shared__ int s_c[WAVES_PER_BLOCK], s_r[WAVES_PER_BLOCK], s_d[WAVES_PER_BLOCK];
    if (lane == 0) { s_c[wave] = my_cind; s_r[wave] = my_rind; s_d[wave] = my_div; }
    __syncthreads();
    const int c_ind = min(min(s_c[0], s_c[1]), min(s_c[2], s_c[3]));
    const int r_pad = min(min(s_r[0], s_r[1]), min(s_r[2], s_r[3]));
    const int fdiv  = min(min(s_d[0], s_d[1]), min(s_d[2], s_d[3]));
    const bool has_div = (fdiv < S);
    const int dv    = has_div ? fdiv : (S - 1);
    const int end   = has_div ? max(c_ind, r_pad) : S;
    const int r_ind = has_div ? r_pad : c_ind;

    // --- live task list: t=0 -> chosen score, t=1 -> rejected score,
    //     t>=2 -> hinge row s = dv + (t-2) ---
    const int nlive = end - dv;
    const int ntask = (nlive > 0 ? nlive : 0) + 2;
    const int t0 = blk * WAVES_PER_BLOCK + wave;

    const float4* hc = (const float4*)(hidden + (size_t)b * S * H);
    const float4* hr = (const float4*)(hidden + (size_t)(b + BS) * S * H);

    float hinge = 0.f;
    for (int t = t0; t < ntask; t += WAVES_PER_PAIR) {
        if (t == 0) {
            const int s = max(c_ind - 1, 0);
            const float4* rc = hc + (size_t)s * (H / 4);
            float ac = 0.f;
#pragma unroll
            for (int c = 0; c < 8; ++c) {
                float4 x = rc[c * 64 + lane];
                ac += x.x * w[c].x + x.y * w[c].y + x.z * w[c].z + x.w * w[c].w;
            }
#pragma unroll
            for (int off = 32; off > 0; off >>= 1) ac += __shfl_xor(ac, off, 64);
            if (lane == 0) out[1 + b] = ac;
        } else if (t == 1) {
            const int s = max(r_ind - 1, 0);
            const float4* rr = hr + (size_t)s * (H / 4);
            float ar = 0.f;
#pragma unroll
            for (int c = 0; c < 8; ++c) {
                float4 y = rr[c * 64 + lane];
                ar += y.x * w[c].x + y.y * w[c].y + y.z * w[c].z + y.w * w[c].w;
            }
#pragma unroll
            for (int off = 32; off > 0; off >>= 1) ar += __shfl_xor(ar, off, 64);
            if (lane == 0) out[9 + b] = ar;
        } else {
            const int s = dv + (t - 2);
            const float4* rc = hc + (size_t)s * (H / 4);
            const float4* rr = hr + (size_t)s * (H / 4);
            float ac = 0.f, ar = 0.f;
#pragma unroll
            for (int c = 0; c < 8; ++c) {
                float4 x = rc[c * 64 + lane];
                float4 y = rr[c * 64 + lane];
                ac += x.x * w[c].x + x.y * w[c].y + x.z * w[c].z + x.w * w[c].w;
                ar += y.x * w[c].x + y.y * w[c].y + y.z * w[c].z + y.w * w[c].w;
            }
#pragma unroll
            for (int off = 32; off > 0; off >>= 1) {
                ac += __shfl_xor(ac, off, 64);
                ar += __shfl_xor(ar, off, 64);
            }
            float h = u - (ac - ar);
            hinge += (h > 0.f) ? h : 0.f;   // all lanes hold same value
        }
    }

    // --- block combine (uniform: every block writes its partial) ---
    __shared__ float s_h[WAVES_PER_BLOCK];
    if (lane == 0) s_h[wave] = hinge;
    __syncthreads();
    if (threadIdx.x == 0) {
        partial[b * BLOCKS_PER_PAIR + blk] = (s_h[0] + s_h[1]) + (s_h[2] + s_h[3]);
        if (blk == 0) { idxbuf[b * 2] = dv; idxbuf[b * 2 + 1] = end; }
    }
}

// ---- Kernel 2: deterministic loss reduction -------------------------------
__global__ __launch_bounds__(512) void loss_kernel(
    const float* __restrict__ partial, // [BS*64]
    const int*   __restrict__ idxbuf,  // [BS*2]
    float* __restrict__ out)           // [17]
{
    const int b    = threadIdx.x >> 6;
    const int lane = threadIdx.x & 63;
    float s = partial[b * BLOCKS_PER_PAIR + lane];
#pragma unroll
    for (int off = 32; off > 0; off >>= 1)
        s += __shfl_xor(s, off, 64);

    __shared__ float s_per[BS];
    if (lane == 0) {
        int cnt = max(idxbuf[b * 2 + 1] - idxbuf[b * 2], 1);
        s_per[b] = s / (float)cnt;
    }
    __syncthreads();
    if (threadIdx.x == 0) {
        float t = 0.f;
#pragma unroll
        for (int i = 0; i < BS; ++i) t += s_per[i];
        out[0] = t / (float)BS;
    }
}

extern "C" void kernel_launch(void* const* d_in, const int* in_sizes, int n_in,
                              void* d_out, int out_size, void* d_ws, size_t ws_size,
                              hipStream_t stream) {
    const float* hidden    = (const float*)d_in[0];
    const int*   input_ids = (const int*)d_in[1];
    const float* unsafe    = (const float*)d_in[2];
    const int*   risk_type = (const int*)d_in[3];
    const float* emb       = (const float*)d_in[4];
    const float* v_w       = (const float*)d_in[5];
    float* out = (float*)d_out;

    int*   idxbuf  = (int*)d_ws;
    float* partial = (float*)((char*)d_ws + 256);

    main_kernel<<<BS * BLOCKS_PER_PAIR, 256, 0, stream>>>(
        hidden, input_ids, unsafe, risk_type, emb, v_w, idxbuf, partial, out);
    loss_kernel<<<1, 512, 0, stream>>>(partial, idxbuf, out);
}

// Round 10
// 16.545 us; speedup vs baseline: 3.4768x; 1.0091x over previous
//
#include <hip/hip_runtime.h>

#define BS 8
#define B2 16
#define S 2048
#define H 2048
#define PAD_ID 0

constexpr int BLOCKS_PER_PAIR = 64;
constexpr int WAVES_PER_BLOCK = 4;
constexpr int WAVES_PER_PAIR  = BLOCKS_PER_PAIR * WAVES_PER_BLOCK; // 256

// ws layout: [0..63]   int idxbuf[BS*2] (div, end)
//            [256..]   float partial[BS*256]  (one per wave)
//
// Waves are fully independent: each wave scans the whole ids pair itself
// (16 KB, L2-resident; loads overlap the w-preload), reduces in-wave, then
// computes its live task. No LDS, no __syncthreads in the main kernel.

__global__ __launch_bounds__(256) void main_kernel(
    const float* __restrict__ hidden,    // [B2, S, H]
    const int*   __restrict__ input_ids, // [B2, S]
    const float* __restrict__ unsafe,    // [BS]
    const int*   __restrict__ risk_type, // [BS]
    const float* __restrict__ emb,       // [N_RISK, H]
    const float* __restrict__ v_w,       // [H]
    int*   __restrict__ idxbuf,          // [BS*2]
    float* __restrict__ partial,         // [BS*256]
    float* __restrict__ out)             // [17]
{
    const int b    = blockIdx.x / BLOCKS_PER_PAIR;
    const int blk  = blockIdx.x % BLOCKS_PER_PAIR;
    const int wave = threadIdx.x >> 6;
    const int lane = threadIdx.x & 63;
    const int t0   = blk * WAVES_PER_BLOCK + wave;

    // --- combined per-lane weights (L2-resident; overlaps the ids scan) ---
    const int rt = risk_type[b];
    float4 w[8];
    {
        const float4* embv = (const float4*)(emb + (size_t)rt * H);
        const float4* vwv  = (const float4*)v_w;
#pragma unroll
        for (int c = 0; c < 8; ++c) {
            int i = c * 64 + lane;
            float4 e = embv[i];
            float4 v = vwv[i];
            w[c] = make_float4(e.x * v.x, e.y * v.y, e.z * v.z, e.w * v.w);
        }
    }
    const float u = unsafe[b];

    // --- wave-private full ids scan: lane covers int4 idx lane+64*it ---
    int my_cind = S, my_rind = S, my_div = S;
    {
        const int4* cid4 = (const int4*)(input_ids + b * S);
        const int4* rid4 = (const int4*)(input_ids + (b + BS) * S);
#pragma unroll
        for (int it = 0; it < 8; ++it) {
            int i = lane + it * 64;
            int4 c4 = cid4[i];
            int4 r4 = rid4[i];
            int base = i * 4;
            int cv[4] = {c4.x, c4.y, c4.z, c4.w};
            int rv[4] = {r4.x, r4.y, r4.z, r4.w};
#pragma unroll
            for (int j = 0; j < 4; ++j) {
                int s = base + j;
                if (cv[j] == PAD_ID && s < my_cind) my_cind = s;
                if (rv[j] == PAD_ID && s < my_rind) my_rind = s;
                if (cv[j] != rv[j]  && s < my_div)  my_div  = s;
            }
        }
#pragma unroll
        for (int off = 32; off > 0; off >>= 1) {
            my_cind = min(my_cind, __shfl_xor(my_cind, off, 64));
            my_rind = min(my_rind, __shfl_xor(my_rind, off, 64));
            my_div  = min(my_div,  __shfl_xor(my_div,  off, 64));
        }
    }
    // all lanes hold the pair-global minima now
    const int c_ind = my_cind;
    const int r_pad = my_rind;
    const bool has_div = (my_div < S);
    const int dv    = has_div ? my_div : (S - 1);
    const int end   = has_div ? max(c_ind, r_pad) : S;
    const int r_ind = has_div ? r_pad : c_ind;

    // --- live task list: t=0 chosen score, t=1 rejected score,
    //     t>=2 hinge row s = dv + (t-2) ---
    const int nlive = end - dv;
    const int ntask = (nlive > 0 ? nlive : 0) + 2;

    const float4* hc = (const float4*)(hidden + (size_t)b * S * H);
    const float4* hr = (const float4*)(hidden + (size_t)(b + BS) * S * H);

    float hinge = 0.f;
    for (int t = t0; t < ntask; t += WAVES_PER_PAIR) {
        if (t == 0) {
            const int s = max(c_ind - 1, 0);
            const float4* rc = hc + (size_t)s * (H / 4);
            float ac = 0.f;
#pragma unroll
            for (int c = 0; c < 8; ++c) {
                float4 x = rc[c * 64 + lane];
                ac += x.x * w[c].x + x.y * w[c].y + x.z * w[c].z + x.w * w[c].w;
            }
#pragma unroll
            for (int off = 32; off > 0; off >>= 1) ac += __shfl_xor(ac, off, 64);
            if (lane == 0) out[1 + b] = ac;
        } else if (t == 1) {
            const int s = max(r_ind - 1, 0);
            const float4* rr = hr + (size_t)s * (H / 4);
            float ar = 0.f;
#pragma unroll
            for (int c = 0; c < 8; ++c) {
                float4 y = rr[c * 64 + lane];
                ar += y.x * w[c].x + y.y * w[c].y + y.z * w[c].z + y.w * w[c].w;
            }
#pragma unroll
            for (int off = 32; off > 0; off >>= 1) ar += __shfl_xor(ar, off, 64);
            if (lane == 0) out[9 + b] = ar;
        } else {
            const int s = dv + (t - 2);
            const float4* rc = hc + (size_t)s * (H / 4);
            const float4* rr = hr + (size_t)s * (H / 4);
            float ac = 0.f, ar = 0.f;
#pragma unroll
            for (int c = 0; c < 8; ++c) {
                float4 x = rc[c * 64 + lane];
                float4 y = rr[c * 64 + lane];
                ac += x.x * w[c].x + x.y * w[c].y + x.z * w[c].z + x.w * w[c].w;
                ar += y.x * w[c].x + y.y * w[c].y + y.z * w[c].z + y.w * w[c].w;
            }
#pragma unroll
            for (int off = 32; off > 0; off >>= 1) {
                ac += __shfl_xor(ac, off, 64);
                ar += __shfl_xor(ar, off, 64);
            }
            float h = u - (ac - ar);
            hinge += (h > 0.f) ? h : 0.f;   // wave-uniform value
        }
    }

    // --- per-wave partial write (no LDS, no sync) ---
    if (lane == 0) {
        partial[b * WAVES_PER_PAIR + t0] = hinge;
        if (t0 == 0) { idxbuf[b * 2] = dv; idxbuf[b * 2 + 1] = end; }
    }
}

// ---- Kernel 2: deterministic loss reduction -------------------------------
__global__ __launch_bounds__(512) void loss_kernel(
    const float* __restrict__ partial, // [BS*256]
    const int*   __restrict__ idxbuf,  // [BS*2]
    float* __restrict__ out)           // [17]
{
    const int b    = threadIdx.x >> 6;
    const int lane = threadIdx.x & 63;
    const float* pb = partial + b * WAVES_PER_PAIR;
    float s = (pb[lane] + pb[64 + lane]) + (pb[128 + lane] + pb[192 + lane]);
#pragma unroll
    for (int off = 32; off > 0; off >>= 1)
        s += __shfl_xor(s, off, 64);

    __shared__ float s_per[BS];
    if (lane == 0) {
        int cnt = max(idxbuf[b * 2 + 1] - idxbuf[b * 2], 1);
        s_per[b] = s / (float)cnt;
    }
    __syncthreads();
    if (threadIdx.x == 0) {
        float t = 0.f;
#pragma unroll
        for (int i = 0; i < BS; ++i) t += s_per[i];
        out[0] = t / (float)BS;
    }
}

extern "C" void kernel_launch(void* const* d_in, const int* in_sizes, int n_in,
                              void* d_out, int out_size, void* d_ws, size_t ws_size,
                              hipStream_t stream) {
    const float* hidden    = (const float*)d_in[0];
    const int*   input_ids = (const int*)d_in[1];
    const float* unsafe    = (const float*)d_in[2];
    const int*   risk_type = (const int*)d_in[3];
    const float* emb       = (const float*)d_in[4];
    const float* v_w       = (const float*)d_in[5];
    float* out = (float*)d_out;

    int*   idxbuf  = (int*)d_ws;
    float* partial = (float*)((char*)d_ws + 256);

    main_kernel<<<BS * BLOCKS_PER_PAIR, 256, 0, stream>>>(
        hidden, input_ids, unsafe, risk_type, emb, v_w, idxbuf, partial, out);
    loss_kernel<<<1, 512, 0, stream>>>(partial, idxbuf, out);
}